// Round 15
// baseline (450.961 us; speedup 1.0000x reference)
//
#include <hip/hip_runtime.h>
#include <math.h>

#define B_ 4
#define S_ 2048
#define D_ 1024
#define H_ 16
#define MLP_ 4096
#define MROWS 8192

typedef __attribute__((ext_vector_type(4))) float f32x4;
typedef __attribute__((ext_vector_type(16))) float f32x16;
typedef __attribute__((ext_vector_type(8))) __bf16 bf16x8;
typedef __attribute__((ext_vector_type(4))) __bf16 bf16x4;
typedef __attribute__((ext_vector_type(8))) unsigned short us8;
typedef unsigned short u16;
typedef unsigned int u32;

__device__ __forceinline__ void gload16(const void* g, void* l) {
    __builtin_amdgcn_global_load_lds((const __attribute__((address_space(1))) u32*)g,
                                     (__attribute__((address_space(3))) u32*)l, 16, 0, 0);
}

// fast GELU: x - x/(e+1), e = exp2(2*log2e*0.7978845608*(x + 0.044715 x^3))
__device__ __forceinline__ float gelu_f(float v) {
    float p = fmaf(v * v, 0.044715f, 1.0f);
    float e = __builtin_amdgcn_exp2f(v * 2.3022089f * p);
    float r = __builtin_amdgcn_rcpf(e + 1.0f);
    return v - v * r;
}

// ---------------- LayerNorm: f32 in -> bf16 out ----------------
__global__ __launch_bounds__(256) void ln_bf16_k(const float* __restrict__ x,
                                                 const float* __restrict__ g,
                                                 const float* __restrict__ b,
                                                 u16* __restrict__ y) {
    int row = blockIdx.x;
    int tid = threadIdx.x;
    const float* xr = x + (size_t)row * D_;
    f32x4 v = *(const f32x4*)(xr + tid * 4);
    float s = v.x + v.y + v.z + v.w;
    float ss = v.x * v.x + v.y * v.y + v.z * v.z + v.w * v.w;
    for (int off = 32; off > 0; off >>= 1) {
        s += __shfl_down(s, off, 64);
        ss += __shfl_down(ss, off, 64);
    }
    __shared__ float rs[4], rss[4];
    int lane = tid & 63, wid = tid >> 6;
    if (lane == 0) { rs[wid] = s; rss[wid] = ss; }
    __syncthreads();
    s = rs[0] + rs[1] + rs[2] + rs[3];
    ss = rss[0] + rss[1] + rss[2] + rss[3];
    float mu = s * (1.0f / D_);
    float var = ss * (1.0f / D_) - mu * mu;
    float inv = rsqrtf(var + 1e-6f);
    f32x4 gg = *(const f32x4*)(g + tid * 4);
    f32x4 bb = *(const f32x4*)(b + tid * 4);
    bf16x4 o = {(__bf16)((v.x - mu) * inv * gg.x + bb.x),
                (__bf16)((v.y - mu) * inv * gg.y + bb.y),
                (__bf16)((v.z - mu) * inv * gg.z + bb.z),
                (__bf16)((v.w - mu) * inv * gg.w + bb.w)};
    *(bf16x4*)(y + (size_t)row * D_ + tid * 4) = o;
}

// ---------------- bias pack: bqkv = [bq*C2|bk|bv] ----------------
__global__ void pack3_k(const float* __restrict__ a, const float* __restrict__ b,
                        const float* __restrict__ c, float* __restrict__ o, float s0) {
    const float* s = blockIdx.x == 0 ? a : (blockIdx.x == 1 ? b : c);
    float sc = blockIdx.x == 0 ? s0 : 1.0f;
    o[blockIdx.x * 1024 + threadIdx.x] = s[threadIdx.x] * sc;
}

// ---------------- weight transpose+convert: W[K,N] f32 -> Wt[N,K] bf16 (×scale) ----------------
__global__ __launch_bounds__(256) void wtrans_k(const float* __restrict__ W,
                                                u16* __restrict__ Wt, int K, int N,
                                                float scale) {
    __shared__ float T[32][33];
    int tid = threadIdx.x;
    int k0 = blockIdx.y * 32, n0 = blockIdx.x * 32;
    int r = tid >> 3, c4 = (tid & 7) * 4;
    f32x4 v = *(const f32x4*)&W[(size_t)(k0 + r) * N + n0 + c4];
    T[r][c4 + 0] = v.x; T[r][c4 + 1] = v.y; T[r][c4 + 2] = v.z; T[r][c4 + 3] = v.w;
    __syncthreads();
    int n = tid >> 3, kk = (tid & 7) * 4;
    bf16x4 o = {(__bf16)(T[kk + 0][n] * scale), (__bf16)(T[kk + 1][n] * scale),
                (__bf16)(T[kk + 2][n] * scale), (__bf16)(T[kk + 3][n] * scale)};
    *(bf16x4*)&Wt[(size_t)(n0 + n) * K + k0 + kk] = o;
}

// ---------------- V transpose (sigma-permuted): QKV V-cols -> Vt [B*H*64][S] ----------------
__device__ __forceinline__ int sigma_perm(int s) {
    return (s & 48) | (s & 3) | (((s >> 2) & 1) << 3) | (((s >> 3) & 1) << 2);
}
__global__ __launch_bounds__(256) void vtrans_k(const u16* __restrict__ QKV,
                                                u16* __restrict__ Vt) {
    __shared__ u16 T[64][80];
    int tid = threadIdx.x;
    int s0 = blockIdx.x * 64;
    int bh = blockIdx.y, b = bh >> 4, h = bh & 15;
    int r = tid >> 2, c0 = (tid & 3) * 16;
    const u16* src = QKV + (size_t)(b * S_ + s0 + r) * 3072 + 2048 + h * 64 + c0;
    us8 v0 = *(const us8*)src;
    us8 v1 = *(const us8*)(src + 8);
    *(us8*)&T[r][c0] = v0;
    *(us8*)&T[r][c0 + 8] = v1;
    __syncthreads();
    int dh = tid >> 2, s8 = (tid & 3) * 16;
    us8 o0, o1;
#pragma unroll
    for (int i = 0; i < 8; ++i) {
        o0[i] = T[sigma_perm(s8 + i)][dh];
        o1[i] = T[sigma_perm(s8 + 8 + i)][dh];
    }
    u16* dst = Vt + (size_t)(bh * 64 + dh) * S_ + s0 + s8;
    *(us8*)dst = o0;
    *(us8*)(dst + 8) = o1;
}

// ---------------- bf16 MFMA GEMM, depth-3 prefetch (4-slot) + chunk-XOR swizzle (128x128) ----------------
// C[M,N] = A[M,K] @ Wt[N,K]^T (+epilogue)
// EPI: 0 = +bias -> bf16 ; 1 = gelu(+bias) -> bf16 ; 2 = +bias +res -> f32
// Ledger: prologue stages tiles 0..2 (12 loads), vmcnt(8) = tile 0 landed.
// Loop t: stage t+3 into slot (bi+3)&3 (that slot was consumed before t-1's end barrier);
// steady-state wait vmcnt(8) = tile t+1 landed, tiles t+2/t+3 (8 loads) in flight. Tail 8->4->0.
template <int EPI>
__global__ __launch_bounds__(256) void gemm_bf16(const u16* __restrict__ A,
                                                 const u16* __restrict__ Wt,
                                                 const float* __restrict__ bias,
                                                 const float* __restrict__ res,
                                                 void* __restrict__ Cout,
                                                 int M, int N, int K) {
    __shared__ u16 As[4][128 * 32];   // 4-slot rotation, 8KB each (64KB total with Bs)
    __shared__ u16 Bs[4][128 * 32];
    const int tid = threadIdx.x;
    const int lane = tid & 63;
    const int w = tid >> 6;
    // XCD-chunked bijective remap (nwg % 8 == 0 for all our grids)
    const int nwg = gridDim.x * gridDim.y;
    int hw = blockIdx.x + gridDim.x * blockIdx.y;
    int lg = (hw & 7) * (nwg >> 3) + (hw >> 3);
    const int row0 = (lg / gridDim.x) * 128;
    const int col0 = (lg % gridDim.x) * 128;
    const int l15 = lane & 15, l16 = lane >> 4;
    const int wr = w >> 1, wc = w & 1;

    f32x4 acc[4][4];
#pragma unroll
    for (int i = 0; i < 4; ++i)
#pragma unroll
        for (int j = 0; j < 4; ++j) acc[i][j] = (f32x4){0.f, 0.f, 0.f, 0.f};

    const int srow = w * 32 + (lane >> 2);
    // chunk-XOR swizzle: source chunk = (lane&3) ^ ((lane>>3)&3)
    const size_t sboff = (size_t)(((lane & 3) ^ ((lane >> 3) & 3)) * 16);
    const char* Ag = (const char*)A + ((size_t)(row0 + srow) * K) * 2 + sboff;
    const char* Bg = (const char*)Wt + ((size_t)(col0 + srow) * K) * 2 + sboff;
    const size_t rstep = (size_t)16 * K * 2;
    const int woff = w * 2048;
    const int T = K >> 5;

#define STAGE(t, bi) do {                                      \
        size_t kb = (size_t)(t) << 6;                          \
        char* asw = (char*)As + (bi) * 8192 + woff;            \
        char* bsw = (char*)Bs + (bi) * 8192 + woff;            \
        gload16(Ag + kb, asw);                                 \
        gload16(Ag + kb + rstep, asw + 1024);                  \
        gload16(Bg + kb, bsw);                                 \
        gload16(Bg + kb + rstep, bsw + 1024);                  \
    } while (0)

    STAGE(0, 0);
    STAGE(1, 1);
    STAGE(2, 2);
    asm volatile("s_waitcnt vmcnt(8)" ::: "memory");   // tile 0 landed; tiles 1,2 in flight
    __builtin_amdgcn_s_barrier();
    __builtin_amdgcn_sched_barrier(0);

    // read-side swizzled chunk offset
    const int ksw = (l16 ^ ((l15 >> 1) & 3)) << 4;
    int bi = 0;
    for (int t = 0; t < T; ++t) {
        if (t + 3 < T) STAGE(t + 3, (bi + 3) & 3);      // prefetch depth 3
        const char* Ab = (const char*)As + bi * 8192;
        const char* Bb = (const char*)Bs + bi * 8192;
        bf16x8 af[4], bfr[4];
#pragma unroll
        for (int f = 0; f < 4; ++f) {
            af[f] = *(const bf16x8*)(Ab + (size_t)(wr * 64 + f * 16 + l15) * 64 + ksw);
            bfr[f] = *(const bf16x8*)(Bb + (size_t)(wc * 64 + f * 16 + l15) * 64 + ksw);
        }
        __builtin_amdgcn_s_setprio(1);
#pragma unroll
        for (int fi = 0; fi < 4; ++fi)
#pragma unroll
            for (int fj = 0; fj < 4; ++fj)
                acc[fi][fj] = __builtin_amdgcn_mfma_f32_16x16x32_bf16(af[fi], bfr[fj], acc[fi][fj], 0, 0, 0);
        __builtin_amdgcn_s_setprio(0);
        if (t + 3 < T) {
            asm volatile("s_waitcnt vmcnt(8)" ::: "memory");   // tile t+1 landed; 8 in flight
        } else if (t + 2 < T) {
            asm volatile("s_waitcnt vmcnt(4)" ::: "memory");   // tile t+1 landed; 4 in flight
        } else {
            asm volatile("s_waitcnt vmcnt(0)" ::: "memory");   // tail drain
        }
        __builtin_amdgcn_s_barrier();
        __builtin_amdgcn_sched_barrier(0);
        bi = (bi + 1) & 3;
    }
#undef STAGE

    const int rb = row0 + wr * 64 + (l16 << 2);
    const int cb = col0 + wc * 64 + l15;
#pragma unroll
    for (int fi = 0; fi < 4; ++fi)
#pragma unroll
        for (int fj = 0; fj < 4; ++fj) {
            int c = cb + fj * 16;
            float bv = bias[c];
#pragma unroll
            for (int rr = 0; rr < 4; ++rr) {
                int r = rb + fi * 16 + rr;
                float v = acc[fi][fj][rr] + bv;
                if (EPI == 1) v = gelu_f(v);
                if (EPI == 2) {
                    v += res[(size_t)r * N + c];
                    ((float*)Cout)[(size_t)r * N + c] = v;
                } else {
                    ((__bf16*)Cout)[(size_t)r * N + c] = (__bf16)v;
                }
            }
        }
}

// ---------------- MFMA flash attention: 32 q/wave, 32x32x16, in-register P ----------------
// Q pre-scaled by 0.125*log2(e) at projection -> P = exp2(score) directly.
// No max-tracking; row-sum via ones-MFMA.
__global__ __launch_bounds__(256) void attn_mfma(const u16* __restrict__ QKV,
                                                 const u16* __restrict__ Vt,
                                                 u16* __restrict__ O) {
    __shared__ u16 Ks[2][64 * 64];
    __shared__ u16 Vs[2][64 * 64];
    const int tid = threadIdx.x, lane = tid & 63, w = tid >> 6;
    int hw = blockIdx.x + gridDim.x * blockIdx.y;
    int lg = (hw & 7) * 128 + (hw >> 3);
    const int bh = lg >> 4, b = bh >> 4, h = bh & 15;
    const int q0 = (lg & 15) * 128;
    const int l31 = lane & 31, lh = lane >> 5;

    const u16* Qp = QKV + (size_t)(b * S_ + q0 + w * 32 + l31) * 3072 + h * 64 + lh * 8;
    bf16x8 qf[4];
    qf[0] = *(const bf16x8*)(Qp);
    qf[1] = *(const bf16x8*)(Qp + 16);
    qf[2] = *(const bf16x8*)(Qp + 32);
    qf[3] = *(const bf16x8*)(Qp + 48);

    f32x16 oacc[2];
    f32x16 lacc;
#pragma unroll
    for (int i = 0; i < 16; ++i) { oacc[0][i] = 0.f; oacc[1][i] = 0.f; lacc[i] = 0.f; }
    bf16x8 ones;
#pragma unroll
    for (int j = 0; j < 8; ++j) ones[j] = (__bf16)1.0f;

    const int sr = lane >> 3;
    const size_t soff = (size_t)(((lane & 7) ^ sr) << 4);
    const char* Kg = (const char*)QKV + ((size_t)b * S_ * 3072 + 1024 + h * 64) * 2;
    const char* Vg = (const char*)Vt + (size_t)bh * 64 * S_ * 2;

    const char* kp0 = Kg + (size_t)(w * 16 + sr) * 6144 + soff;
    const char* kp1 = kp0 + 8 * 6144;
    const char* vp0 = Vg + (size_t)(w * 16 + sr) * 4096 + soff;
    const char* vp1 = vp0 + 8 * 4096;
    const size_t KADV = 64 * 6144;
    const size_t VADV = 128;
    char* ksA = (char*)Ks[0] + w * 2048;
    char* ksB = (char*)Ks[1] + w * 2048;
    char* vsA = (char*)Vs[0] + w * 2048;
    char* vsB = (char*)Vs[1] + w * 2048;

    gload16(kp0, ksA); gload16(kp1, ksA + 1024);
    gload16(vp0, vsA); gload16(vp1, vsA + 1024);
    kp0 += KADV; kp1 += KADV; vp0 += VADV; vp1 += VADV;
    __syncthreads();

    for (int kt = 0; kt < S_ / 64; ++kt) {
        const int cur = kt & 1;
        if (kt < S_ / 64 - 1) {
            char* kd = cur ? ksA : ksB;
            char* vd = cur ? vsA : vsB;
            gload16(kp0, kd); gload16(kp1, kd + 1024);
            gload16(vp0, vd); gload16(vp1, vd + 1024);
            kp0 += KADV; kp1 += KADV; vp0 += VADV; vp1 += VADV;
        }

        const char* Kb_ = (const char*)Ks[cur];
        f32x16 sfr[2];
        __builtin_amdgcn_s_setprio(1);
#pragma unroll
        for (int kh = 0; kh < 2; ++kh) {
            int r = kh * 32 + l31;
            int rsw = (r & 7) << 4;
            const char* Kr = Kb_ + r * 128;
            f32x16 t;
#pragma unroll
            for (int i = 0; i < 16; ++i) t[i] = 0.f;
#pragma unroll
            for (int ds = 0; ds < 4; ++ds) {
                bf16x8 kf = *(const bf16x8*)(Kr + ((((ds * 2 + lh) << 4)) ^ rsw));
                t = __builtin_amdgcn_mfma_f32_32x32x16_bf16(kf, qf[ds], t, 0, 0, 0);
            }
            sfr[kh] = t;
        }
        __builtin_amdgcn_s_setprio(0);

        float pv0[16], pv1[16];
#pragma unroll
        for (int i = 0; i < 16; ++i) {
            pv0[i] = __builtin_amdgcn_exp2f(sfr[0][i]);
            pv1[i] = __builtin_amdgcn_exp2f(sfr[1][i]);
        }

        bf16x8 pf[4];
#pragma unroll
        for (int j = 0; j < 8; ++j) {
            pf[0][j] = (__bf16)pv0[j];
            pf[1][j] = (__bf16)pv0[8 + j];
            pf[2][j] = (__bf16)pv1[j];
            pf[3][j] = (__bf16)pv1[8 + j];
        }

        {
            const char* Vb_ = (const char*)Vs[cur];
            __builtin_amdgcn_s_setprio(1);
#pragma unroll
            for (int ks = 0; ks < 4; ++ks)
                lacc = __builtin_amdgcn_mfma_f32_32x32x16_bf16(ones, pf[ks], lacc, 0, 0, 0);
#pragma unroll
            for (int dh = 0; dh < 2; ++dh) {
                int r = dh * 32 + l31;
                int rsw = (r & 7) << 4;
                const char* Vr = Vb_ + r * 128;
#pragma unroll
                for (int ks = 0; ks < 4; ++ks) {
                    bf16x8 vf = *(const bf16x8*)(Vr + ((((ks * 2 + lh) << 4)) ^ rsw));
                    oacc[dh] = __builtin_amdgcn_mfma_f32_32x32x16_bf16(vf, pf[ks], oacc[dh], 0, 0, 0);
                }
            }
            __builtin_amdgcn_s_setprio(0);
        }
        __syncthreads();
    }

    float invl = 1.0f / lacc[0];
    char* Og = (char*)O + ((size_t)(b * S_ + q0 + w * 32 + l31) * 1024 + h * 64) * 2;
#pragma unroll
    for (int dh = 0; dh < 2; ++dh)
#pragma unroll
        for (int t4 = 0; t4 < 4; ++t4) {
            int db = dh * 32 + t4 * 8 + lh * 4;
            bf16x4 ov = {(__bf16)(oacc[dh][t4 * 4] * invl),
                         (__bf16)(oacc[dh][t4 * 4 + 1] * invl),
                         (__bf16)(oacc[dh][t4 * 4 + 2] * invl),
                         (__bf16)(oacc[dh][t4 * 4 + 3] * invl)};
            *(bf16x4*)(Og + db * 2) = ov;
        }
}

// ---------------- launch ----------------
extern "C" void kernel_launch(void* const* d_in, const int* in_sizes, int n_in,
                              void* d_out, int out_size, void* d_ws, size_t ws_size,
                              hipStream_t stream) {
    const float* x     = (const float*)d_in[0];
    const float* Wq    = (const float*)d_in[1];
    const float* bq    = (const float*)d_in[2];
    const float* Wk    = (const float*)d_in[3];
    const float* bk    = (const float*)d_in[4];
    const float* Wv    = (const float*)d_in[5];
    const float* bv    = (const float*)d_in[6];
    const float* Wo    = (const float*)d_in[7];
    const float* bo    = (const float*)d_in[8];
    const float* ln1_g = (const float*)d_in[9];
    const float* ln1_b = (const float*)d_in[10];
    const float* ln2_g = (const float*)d_in[11];
    const float* ln2_b = (const float*)d_in[12];
    const float* W1    = (const float*)d_in[13];
    const float* b1    = (const float*)d_in[14];
    const float* W2    = (const float*)d_in[15];
    const float* b2    = (const float*)d_in[16];
    float* out = (float*)d_out;
    const float C2 = 0.18033688011112f;   // 0.125 * log2(e)

    const size_t MB = 1ull << 20;
    char* ws = (char*)d_ws;
    u16* QKVb = (u16*)(ws + 0 * MB);      // 48MB [8192][3072]
    u16* aout = (u16*)(ws + 48 * MB);     // 16MB [8192][1024]
    u16* mid  = (u16*)(ws + 0 * MB);      // 64MB [8192][4096]
    float* x2 = (float*)(ws + 64 * MB);   // 32MB f32
    float* bqkv = (float*)(ws + 64 * MB); // 12KB (dead once x2 is written)
    u16* xn   = (u16*)(ws + 96 * MB);     // 16MB
    u16* Vt   = (u16*)(ws + 96 * MB);     // reuses xn after QKV
    u16* xn2  = (u16*)(ws + 96 * MB);     // reuses Vt after attn
    u16* Wqkvt = (u16*)(ws + 112 * MB);   // 6MB [3072][1024]
    u16* Wot  = Wqkvt + (size_t)3072 * D_;// 2MB
    u16* W1t  = (u16*)(ws + 112 * MB);    // 8MB (reuses Wqkvt+Wot)
    u16* W2t  = (u16*)(ws + 120 * MB);    // 8MB

    // weight conversions + bias pack (Wq/bq pre-scaled by C2)
    wtrans_k<<<dim3(32, 32), 256, 0, stream>>>(Wq, Wqkvt, D_, D_, C2);
    wtrans_k<<<dim3(32, 32), 256, 0, stream>>>(Wk, Wqkvt + (size_t)D_ * D_, D_, D_, 1.0f);
    wtrans_k<<<dim3(32, 32), 256, 0, stream>>>(Wv, Wqkvt + (size_t)2 * D_ * D_, D_, D_, 1.0f);
    wtrans_k<<<dim3(32, 32), 256, 0, stream>>>(Wo, Wot, D_, D_, 1.0f);
    wtrans_k<<<dim3(32, 128), 256, 0, stream>>>(W2, W2t, MLP_, D_, 1.0f);
    pack3_k<<<3, 1024, 0, stream>>>(bq, bk, bv, bqkv, C2);

    // LN1
    ln_bf16_k<<<MROWS, 256, 0, stream>>>(x, ln1_g, ln1_b, xn);
    // fused QKV projection: [8192][3072]
    gemm_bf16<0><<<dim3(24, 64), 256, 0, stream>>>(xn, Wqkvt, bqkv, nullptr, QKVb, MROWS, 3072, D_);
    // V transpose per head (sigma-permuted columns)
    vtrans_k<<<dim3(32, 64), 256, 0, stream>>>(QKVb, Vt);
    // attention (128 queries/block)
    attn_mfma<<<dim3(16, 64), 256, 0, stream>>>(QKVb, Vt, aout);
    // out projection + residual -> x2 (f32)
    gemm_bf16<2><<<dim3(8, 64), 256, 0, stream>>>(aout, Wot, bo, x, x2, MROWS, D_, D_);
    // W1 transpose, LN2
    wtrans_k<<<dim3(128, 32), 256, 0, stream>>>(W1, W1t, D_, MLP_, 1.0f);
    ln_bf16_k<<<MROWS, 256, 0, stream>>>(x2, ln2_g, ln2_b, xn2);
    // MLP
    gemm_bf16<1><<<dim3(32, 64), 256, 0, stream>>>(xn2, W1t, b1, nullptr, mid, MROWS, MLP_, D_);
    gemm_bf16<2><<<dim3(8, 64), 256, 0, stream>>>(mid, W2t, b2, x2, (void*)out, MROWS, D_, MLP_);
}

// Round 16
// 417.900 us; speedup vs baseline: 1.0791x; 1.0791x over previous
//
#include <hip/hip_runtime.h>
#include <math.h>

#define B_ 4
#define S_ 2048
#define D_ 1024
#define H_ 16
#define MLP_ 4096
#define MROWS 8192

typedef __attribute__((ext_vector_type(4))) float f32x4;
typedef __attribute__((ext_vector_type(16))) float f32x16;
typedef __attribute__((ext_vector_type(8))) __bf16 bf16x8;
typedef __attribute__((ext_vector_type(4))) __bf16 bf16x4;
typedef __attribute__((ext_vector_type(8))) unsigned short us8;
typedef unsigned short u16;
typedef unsigned int u32;

__device__ __forceinline__ void gload16(const void* g, void* l) {
    __builtin_amdgcn_global_load_lds((const __attribute__((address_space(1))) u32*)g,
                                     (__attribute__((address_space(3))) u32*)l, 16, 0, 0);
}

// fast GELU: x - x/(e+1), e = exp2(2*log2e*0.7978845608*(x + 0.044715 x^3))
__device__ __forceinline__ float gelu_f(float v) {
    float p = fmaf(v * v, 0.044715f, 1.0f);
    float e = __builtin_amdgcn_exp2f(v * 2.3022089f * p);
    float r = __builtin_amdgcn_rcpf(e + 1.0f);
    return v - v * r;
}

// ---------------- LayerNorm: f32 in -> bf16 out ----------------
__global__ __launch_bounds__(256) void ln_bf16_k(const float* __restrict__ x,
                                                 const float* __restrict__ g,
                                                 const float* __restrict__ b,
                                                 u16* __restrict__ y) {
    int row = blockIdx.x;
    int tid = threadIdx.x;
    const float* xr = x + (size_t)row * D_;
    f32x4 v = *(const f32x4*)(xr + tid * 4);
    float s = v.x + v.y + v.z + v.w;
    float ss = v.x * v.x + v.y * v.y + v.z * v.z + v.w * v.w;
    for (int off = 32; off > 0; off >>= 1) {
        s += __shfl_down(s, off, 64);
        ss += __shfl_down(ss, off, 64);
    }
    __shared__ float rs[4], rss[4];
    int lane = tid & 63, wid = tid >> 6;
    if (lane == 0) { rs[wid] = s; rss[wid] = ss; }
    __syncthreads();
    s = rs[0] + rs[1] + rs[2] + rs[3];
    ss = rss[0] + rss[1] + rss[2] + rss[3];
    float mu = s * (1.0f / D_);
    float var = ss * (1.0f / D_) - mu * mu;
    float inv = rsqrtf(var + 1e-6f);
    f32x4 gg = *(const f32x4*)(g + tid * 4);
    f32x4 bb = *(const f32x4*)(b + tid * 4);
    bf16x4 o = {(__bf16)((v.x - mu) * inv * gg.x + bb.x),
                (__bf16)((v.y - mu) * inv * gg.y + bb.y),
                (__bf16)((v.z - mu) * inv * gg.z + bb.z),
                (__bf16)((v.w - mu) * inv * gg.w + bb.w)};
    *(bf16x4*)(y + (size_t)row * D_ + tid * 4) = o;
}

// ---------------- bias pack: bqkv = [bq*C2|bk|bv] ----------------
__global__ void pack3_k(const float* __restrict__ a, const float* __restrict__ b,
                        const float* __restrict__ c, float* __restrict__ o, float s0) {
    const float* s = blockIdx.x == 0 ? a : (blockIdx.x == 1 ? b : c);
    float sc = blockIdx.x == 0 ? s0 : 1.0f;
    o[blockIdx.x * 1024 + threadIdx.x] = s[threadIdx.x] * sc;
}

// ---------------- weight transpose+convert: W[K,N] f32 -> Wt[N,K] bf16 (×scale) ----------------
__global__ __launch_bounds__(256) void wtrans_k(const float* __restrict__ W,
                                                u16* __restrict__ Wt, int K, int N,
                                                float scale) {
    __shared__ float T[32][33];
    int tid = threadIdx.x;
    int k0 = blockIdx.y * 32, n0 = blockIdx.x * 32;
    int r = tid >> 3, c4 = (tid & 7) * 4;
    f32x4 v = *(const f32x4*)&W[(size_t)(k0 + r) * N + n0 + c4];
    T[r][c4 + 0] = v.x; T[r][c4 + 1] = v.y; T[r][c4 + 2] = v.z; T[r][c4 + 3] = v.w;
    __syncthreads();
    int n = tid >> 3, kk = (tid & 7) * 4;
    bf16x4 o = {(__bf16)(T[kk + 0][n] * scale), (__bf16)(T[kk + 1][n] * scale),
                (__bf16)(T[kk + 2][n] * scale), (__bf16)(T[kk + 3][n] * scale)};
    *(bf16x4*)&Wt[(size_t)(n0 + n) * K + k0 + kk] = o;
}

// ---------------- merged 4x 1024x1024 transpose: Wq,Wk,Wv,Wo -> Wqkvt[4*D*D] ----------------
__global__ __launch_bounds__(256) void wtrans4_k(const float* __restrict__ W0,
                                                 const float* __restrict__ W1,
                                                 const float* __restrict__ W2,
                                                 const float* __restrict__ W3,
                                                 u16* __restrict__ Wt, float s0) {
    __shared__ float T[32][33];
    const float* W = blockIdx.z == 0 ? W0 : (blockIdx.z == 1 ? W1 : (blockIdx.z == 2 ? W2 : W3));
    float scale = blockIdx.z == 0 ? s0 : 1.0f;
    u16* dst = Wt + (size_t)blockIdx.z * D_ * D_;
    int tid = threadIdx.x;
    int k0 = blockIdx.y * 32, n0 = blockIdx.x * 32;
    int r = tid >> 3, c4 = (tid & 7) * 4;
    f32x4 v = *(const f32x4*)&W[(size_t)(k0 + r) * D_ + n0 + c4];
    T[r][c4 + 0] = v.x; T[r][c4 + 1] = v.y; T[r][c4 + 2] = v.z; T[r][c4 + 3] = v.w;
    __syncthreads();
    int n = tid >> 3, kk = (tid & 7) * 4;
    bf16x4 o = {(__bf16)(T[kk + 0][n] * scale), (__bf16)(T[kk + 1][n] * scale),
                (__bf16)(T[kk + 2][n] * scale), (__bf16)(T[kk + 3][n] * scale)};
    *(bf16x4*)&dst[(size_t)(n0 + n) * D_ + k0 + kk] = o;
}

// ---------------- V transpose (sigma-permuted): QKV V-cols -> Vt [B*H*64][S] ----------------
__device__ __forceinline__ int sigma_perm(int s) {
    return (s & 48) | (s & 3) | (((s >> 2) & 1) << 3) | (((s >> 3) & 1) << 2);
}
__global__ __launch_bounds__(256) void vtrans_k(const u16* __restrict__ QKV,
                                                u16* __restrict__ Vt) {
    __shared__ u16 T[64][80];
    int tid = threadIdx.x;
    int s0 = blockIdx.x * 64;
    int bh = blockIdx.y, b = bh >> 4, h = bh & 15;
    int r = tid >> 2, c0 = (tid & 3) * 16;
    const u16* src = QKV + (size_t)(b * S_ + s0 + r) * 3072 + 2048 + h * 64 + c0;
    us8 v0 = *(const us8*)src;
    us8 v1 = *(const us8*)(src + 8);
    *(us8*)&T[r][c0] = v0;
    *(us8*)&T[r][c0 + 8] = v1;
    __syncthreads();
    int dh = tid >> 2, s8 = (tid & 3) * 16;
    us8 o0, o1;
#pragma unroll
    for (int i = 0; i < 8; ++i) {
        o0[i] = T[sigma_perm(s8 + i)][dh];
        o1[i] = T[sigma_perm(s8 + 8 + i)][dh];
    }
    u16* dst = Vt + (size_t)(bh * 64 + dh) * S_ + s0 + s8;
    *(us8*)dst = o0;
    *(us8*)(dst + 8) = o1;
}

// ---------------- bf16 MFMA GEMM, depth-2 prefetch + chunk-XOR LDS swizzle (128x128) ----------------
// C[M,N] = A[M,K] @ Wt[N,K]^T (+epilogue)
// EPI: 0 = +bias -> bf16 ; 1 = gelu(+bias) -> bf16 ; 2 = +bias +res -> f32
template <int EPI>
__global__ __launch_bounds__(256) void gemm_bf16(const u16* __restrict__ A,
                                                 const u16* __restrict__ Wt,
                                                 const float* __restrict__ bias,
                                                 const float* __restrict__ res,
                                                 void* __restrict__ Cout,
                                                 int M, int N, int K) {
    __shared__ u16 As[3][128 * 32];   // 3-deep rotation, 8KB each (48KB total -> 3 blocks/CU)
    __shared__ u16 Bs[3][128 * 32];
    const int tid = threadIdx.x;
    const int lane = tid & 63;
    const int w = tid >> 6;
    // XCD-chunked bijective remap (nwg % 8 == 0 for all our grids)
    const int nwg = gridDim.x * gridDim.y;
    int hw = blockIdx.x + gridDim.x * blockIdx.y;
    int lg = (hw & 7) * (nwg >> 3) + (hw >> 3);
    const int row0 = (lg / gridDim.x) * 128;
    const int col0 = (lg % gridDim.x) * 128;
    const int l15 = lane & 15, l16 = lane >> 4;
    const int wr = w >> 1, wc = w & 1;

    f32x4 acc[4][4];
#pragma unroll
    for (int i = 0; i < 4; ++i)
#pragma unroll
        for (int j = 0; j < 4; ++j) acc[i][j] = (f32x4){0.f, 0.f, 0.f, 0.f};

    const int srow = w * 32 + (lane >> 2);
    // chunk-XOR swizzle: source chunk = (lane&3) ^ ((lane>>3)&3)
    const size_t sboff = (size_t)(((lane & 3) ^ ((lane >> 3) & 3)) * 16);
    const char* Ag = (const char*)A + ((size_t)(row0 + srow) * K) * 2 + sboff;
    const char* Bg = (const char*)Wt + ((size_t)(col0 + srow) * K) * 2 + sboff;
    const size_t rstep = (size_t)16 * K * 2;
    const int woff = w * 2048;
    const int T = K >> 5;

#define STAGE(t, bi) do {                                      \
        size_t kb = (size_t)(t) << 6;                          \
        char* asw = (char*)As + (bi) * 8192 + woff;            \
        char* bsw = (char*)Bs + (bi) * 8192 + woff;            \
        gload16(Ag + kb, asw);                                 \
        gload16(Ag + kb + rstep, asw + 1024);                  \
        gload16(Bg + kb, bsw);                                 \
        gload16(Bg + kb + rstep, bsw + 1024);                  \
    } while (0)

    STAGE(0, 0);
    STAGE(1, 1);
    asm volatile("s_waitcnt vmcnt(4)" ::: "memory");   // tile 0 landed; tile 1 in flight
    __builtin_amdgcn_s_barrier();
    __builtin_amdgcn_sched_barrier(0);

    // read-side swizzled chunk offset
    const int ksw = (l16 ^ ((l15 >> 1) & 3)) << 4;
    int bi = 0;
    for (int t = 0; t < T; ++t) {
        if (t + 2 < T) {
            int nb = bi + 2; if (nb >= 3) nb -= 3;
            STAGE(t + 2, nb);                           // prefetch stays in flight
        }
        const char* Ab = (const char*)As + bi * 8192;
        const char* Bb = (const char*)Bs + bi * 8192;
        bf16x8 af[4], bfr[4];
#pragma unroll
        for (int f = 0; f < 4; ++f) {
            af[f] = *(const bf16x8*)(Ab + (size_t)(wr * 64 + f * 16 + l15) * 64 + ksw);
            bfr[f] = *(const bf16x8*)(Bb + (size_t)(wc * 64 + f * 16 + l15) * 64 + ksw);
        }
        __builtin_amdgcn_s_setprio(1);
#pragma unroll
        for (int fi = 0; fi < 4; ++fi)
#pragma unroll
            for (int fj = 0; fj < 4; ++fj)
                acc[fi][fj] = __builtin_amdgcn_mfma_f32_16x16x32_bf16(af[fi], bfr[fj], acc[fi][fj], 0, 0, 0);
        __builtin_amdgcn_s_setprio(0);
        if (t + 2 < T) {
            asm volatile("s_waitcnt vmcnt(4)" ::: "memory");   // tile t+1 landed, t+2 in flight
        } else {
            asm volatile("s_waitcnt vmcnt(0)" ::: "memory");   // tail drain
        }
        __builtin_amdgcn_s_barrier();
        __builtin_amdgcn_sched_barrier(0);
        if (++bi >= 3) bi = 0;
    }
#undef STAGE

    const int rb = row0 + wr * 64 + (l16 << 2);
    const int cb = col0 + wc * 64 + l15;
#pragma unroll
    for (int fi = 0; fi < 4; ++fi)
#pragma unroll
        for (int fj = 0; fj < 4; ++fj) {
            int c = cb + fj * 16;
            float bv = bias[c];
#pragma unroll
            for (int rr = 0; rr < 4; ++rr) {
                int r = rb + fi * 16 + rr;
                float v = acc[fi][fj][rr] + bv;
                if (EPI == 1) v = gelu_f(v);
                if (EPI == 2) {
                    v += res[(size_t)r * N + c];
                    ((float*)Cout)[(size_t)r * N + c] = v;
                } else {
                    ((__bf16*)Cout)[(size_t)r * N + c] = (__bf16)v;
                }
            }
        }
}

// ---------------- MFMA flash attention: 32 q/wave, 32x32x16, in-register P ----------------
// Q pre-scaled by 0.125*log2(e) at projection -> P = exp2(score) directly.
// No max-tracking; row-sum via ones-MFMA.
__global__ __launch_bounds__(256) void attn_mfma(const u16* __restrict__ QKV,
                                                 const u16* __restrict__ Vt,
                                                 u16* __restrict__ O) {
    __shared__ u16 Ks[2][64 * 64];
    __shared__ u16 Vs[2][64 * 64];
    const int tid = threadIdx.x, lane = tid & 63, w = tid >> 6;
    int hw = blockIdx.x + gridDim.x * blockIdx.y;
    int lg = (hw & 7) * 128 + (hw >> 3);
    const int bh = lg >> 4, b = bh >> 4, h = bh & 15;
    const int q0 = (lg & 15) * 128;
    const int l31 = lane & 31, lh = lane >> 5;

    const u16* Qp = QKV + (size_t)(b * S_ + q0 + w * 32 + l31) * 3072 + h * 64 + lh * 8;
    bf16x8 qf[4];
    qf[0] = *(const bf16x8*)(Qp);
    qf[1] = *(const bf16x8*)(Qp + 16);
    qf[2] = *(const bf16x8*)(Qp + 32);
    qf[3] = *(const bf16x8*)(Qp + 48);

    f32x16 oacc[2];
    f32x16 lacc;
#pragma unroll
    for (int i = 0; i < 16; ++i) { oacc[0][i] = 0.f; oacc[1][i] = 0.f; lacc[i] = 0.f; }
    bf16x8 ones;
#pragma unroll
    for (int j = 0; j < 8; ++j) ones[j] = (__bf16)1.0f;

    const int sr = lane >> 3;
    const size_t soff = (size_t)(((lane & 7) ^ sr) << 4);
    const char* Kg = (const char*)QKV + ((size_t)b * S_ * 3072 + 1024 + h * 64) * 2;
    const char* Vg = (const char*)Vt + (size_t)bh * 64 * S_ * 2;

    const char* kp0 = Kg + (size_t)(w * 16 + sr) * 6144 + soff;
    const char* kp1 = kp0 + 8 * 6144;
    const char* vp0 = Vg + (size_t)(w * 16 + sr) * 4096 + soff;
    const char* vp1 = vp0 + 8 * 4096;
    const size_t KADV = 64 * 6144;
    const size_t VADV = 128;
    char* ksA = (char*)Ks[0] + w * 2048;
    char* ksB = (char*)Ks[1] + w * 2048;
    char* vsA = (char*)Vs[0] + w * 2048;
    char* vsB = (char*)Vs[1] + w * 2048;

    gload16(kp0, ksA); gload16(kp1, ksA + 1024);
    gload16(vp0, vsA); gload16(vp1, vsA + 1024);
    kp0 += KADV; kp1 += KADV; vp0 += VADV; vp1 += VADV;
    __syncthreads();

    for (int kt = 0; kt < S_ / 64; ++kt) {
        const int cur = kt & 1;
        if (kt < S_ / 64 - 1) {
            char* kd = cur ? ksA : ksB;
            char* vd = cur ? vsA : vsB;
            gload16(kp0, kd); gload16(kp1, kd + 1024);
            gload16(vp0, vd); gload16(vp1, vd + 1024);
            kp0 += KADV; kp1 += KADV; vp0 += VADV; vp1 += VADV;
        }

        const char* Kb_ = (const char*)Ks[cur];
        f32x16 sfr[2];
        __builtin_amdgcn_s_setprio(1);
#pragma unroll
        for (int kh = 0; kh < 2; ++kh) {
            int r = kh * 32 + l31;
            int rsw = (r & 7) << 4;
            const char* Kr = Kb_ + r * 128;
            f32x16 t;
#pragma unroll
            for (int i = 0; i < 16; ++i) t[i] = 0.f;
#pragma unroll
            for (int ds = 0; ds < 4; ++ds) {
                bf16x8 kf = *(const bf16x8*)(Kr + ((((ds * 2 + lh) << 4)) ^ rsw));
                t = __builtin_amdgcn_mfma_f32_32x32x16_bf16(kf, qf[ds], t, 0, 0, 0);
            }
            sfr[kh] = t;
        }
        __builtin_amdgcn_s_setprio(0);

        float pv0[16], pv1[16];
#pragma unroll
        for (int i = 0; i < 16; ++i) {
            pv0[i] = __builtin_amdgcn_exp2f(sfr[0][i]);
            pv1[i] = __builtin_amdgcn_exp2f(sfr[1][i]);
        }

        bf16x8 pf[4];
#pragma unroll
        for (int j = 0; j < 8; ++j) {
            pf[0][j] = (__bf16)pv0[j];
            pf[1][j] = (__bf16)pv0[8 + j];
            pf[2][j] = (__bf16)pv1[j];
            pf[3][j] = (__bf16)pv1[8 + j];
        }

        {
            const char* Vb_ = (const char*)Vs[cur];
            __builtin_amdgcn_s_setprio(1);
#pragma unroll
            for (int ks = 0; ks < 4; ++ks)
                lacc = __builtin_amdgcn_mfma_f32_32x32x16_bf16(ones, pf[ks], lacc, 0, 0, 0);
#pragma unroll
            for (int dh = 0; dh < 2; ++dh) {
                int r = dh * 32 + l31;
                int rsw = (r & 7) << 4;
                const char* Vr = Vb_ + r * 128;
#pragma unroll
                for (int ks = 0; ks < 4; ++ks) {
                    bf16x8 vf = *(const bf16x8*)(Vr + ((((ks * 2 + lh) << 4)) ^ rsw));
                    oacc[dh] = __builtin_amdgcn_mfma_f32_32x32x16_bf16(vf, pf[ks], oacc[dh], 0, 0, 0);
                }
            }
            __builtin_amdgcn_s_setprio(0);
        }
        __syncthreads();
    }

    float invl = 1.0f / lacc[0];
    char* Og = (char*)O + ((size_t)(b * S_ + q0 + w * 32 + l31) * 1024 + h * 64) * 2;
#pragma unroll
    for (int dh = 0; dh < 2; ++dh)
#pragma unroll
        for (int t4 = 0; t4 < 4; ++t4) {
            int db = dh * 32 + t4 * 8 + lh * 4;
            bf16x4 ov = {(__bf16)(oacc[dh][t4 * 4] * invl),
                         (__bf16)(oacc[dh][t4 * 4 + 1] * invl),
                         (__bf16)(oacc[dh][t4 * 4 + 2] * invl),
                         (__bf16)(oacc[dh][t4 * 4 + 3] * invl)};
            *(bf16x4*)(Og + db * 2) = ov;
        }
}

// ---------------- launch ----------------
extern "C" void kernel_launch(void* const* d_in, const int* in_sizes, int n_in,
                              void* d_out, int out_size, void* d_ws, size_t ws_size,
                              hipStream_t stream) {
    const float* x     = (const float*)d_in[0];
    const float* Wq    = (const float*)d_in[1];
    const float* bq    = (const float*)d_in[2];
    const float* Wk    = (const float*)d_in[3];
    const float* bk    = (const float*)d_in[4];
    const float* Wv    = (const float*)d_in[5];
    const float* bv    = (const float*)d_in[6];
    const float* Wo    = (const float*)d_in[7];
    const float* bo    = (const float*)d_in[8];
    const float* ln1_g = (const float*)d_in[9];
    const float* ln1_b = (const float*)d_in[10];
    const float* ln2_g = (const float*)d_in[11];
    const float* ln2_b = (const float*)d_in[12];
    const float* W1    = (const float*)d_in[13];
    const float* b1    = (const float*)d_in[14];
    const float* W2    = (const float*)d_in[15];
    const float* b2    = (const float*)d_in[16];
    float* out = (float*)d_out;
    const float C2 = 0.18033688011112f;   // 0.125 * log2(e)

    const size_t MB = 1ull << 20;
    char* ws = (char*)d_ws;
    u16* QKVb = (u16*)(ws + 0 * MB);      // 48MB [8192][3072]
    u16* aout = (u16*)(ws + 48 * MB);     // 16MB [8192][1024]
    u16* mid  = (u16*)(ws + 0 * MB);      // 64MB [8192][4096]
    float* x2 = (float*)(ws + 64 * MB);   // 32MB f32
    float* bqkv = (float*)(ws + 64 * MB); // 12KB (dead once x2 is written)
    u16* xn   = (u16*)(ws + 96 * MB);     // 16MB
    u16* Vt   = (u16*)(ws + 96 * MB);     // reuses xn after QKV
    u16* xn2  = (u16*)(ws + 96 * MB);     // reuses Vt after attn
    u16* Wqkvt = (u16*)(ws + 112 * MB);   // 8MB [4096][1024]: Wq,Wk,Wv,Wo transposed
    u16* Wot  = Wqkvt + (size_t)3 * D_ * D_;
    u16* W1t  = (u16*)(ws + 112 * MB);    // 8MB (reuses Wqkvt+Wot after out-proj)
    u16* W2t  = (u16*)(ws + 120 * MB);    // 8MB

    // weight conversions + bias pack (Wq/bq pre-scaled by C2); 4x 1024x1024 merged
    wtrans4_k<<<dim3(32, 32, 4), 256, 0, stream>>>(Wq, Wk, Wv, Wo, Wqkvt, C2);
    wtrans_k<<<dim3(32, 128), 256, 0, stream>>>(W2, W2t, MLP_, D_, 1.0f);
    pack3_k<<<3, 1024, 0, stream>>>(bq, bk, bv, bqkv, C2);

    // LN1
    ln_bf16_k<<<MROWS, 256, 0, stream>>>(x, ln1_g, ln1_b, xn);
    // fused QKV projection: [8192][3072]
    gemm_bf16<0><<<dim3(24, 64), 256, 0, stream>>>(xn, Wqkvt, bqkv, nullptr, QKVb, MROWS, 3072, D_);
    // V transpose per head (sigma-permuted columns)
    vtrans_k<<<dim3(32, 64), 256, 0, stream>>>(QKVb, Vt);
    // attention (128 queries/block)
    attn_mfma<<<dim3(16, 64), 256, 0, stream>>>(QKVb, Vt, aout);
    // out projection + residual -> x2 (f32)
    gemm_bf16<2><<<dim3(8, 64), 256, 0, stream>>>(aout, Wot, bo, x, x2, MROWS, D_, D_);
    // W1 transpose, LN2
    wtrans_k<<<dim3(128, 32), 256, 0, stream>>>(W1, W1t, D_, MLP_, 1.0f);
    ln_bf16_k<<<MROWS, 256, 0, stream>>>(x2, ln2_g, ln2_b, xn2);
    // MLP
    gemm_bf16<1><<<dim3(32, 64), 256, 0, stream>>>(xn2, W1t, b1, nullptr, mid, MROWS, MLP_, D_);
    gemm_bf16<2><<<dim3(8, 64), 256, 0, stream>>>(mid, W2t, b2, x2, (void*)out, MROWS, D_, MLP_);
}

// Round 17
// 413.205 us; speedup vs baseline: 1.0914x; 1.0114x over previous
//
#include <hip/hip_runtime.h>
#include <math.h>

#define B_ 4
#define S_ 2048
#define D_ 1024
#define H_ 16
#define MLP_ 4096
#define MROWS 8192

typedef __attribute__((ext_vector_type(4))) float f32x4;
typedef __attribute__((ext_vector_type(16))) float f32x16;
typedef __attribute__((ext_vector_type(8))) __bf16 bf16x8;
typedef __attribute__((ext_vector_type(4))) __bf16 bf16x4;
typedef __attribute__((ext_vector_type(8))) unsigned short us8;
typedef unsigned short u16;
typedef unsigned int u32;

__device__ __forceinline__ void gload16(const void* g, void* l) {
    __builtin_amdgcn_global_load_lds((const __attribute__((address_space(1))) u32*)g,
                                     (__attribute__((address_space(3))) u32*)l, 16, 0, 0);
}

// fast GELU: x - x/(e+1), e = exp2(2*log2e*0.7978845608*(x + 0.044715 x^3))
__device__ __forceinline__ float gelu_f(float v) {
    float p = fmaf(v * v, 0.044715f, 1.0f);
    float e = __builtin_amdgcn_exp2f(v * 2.3022089f * p);
    float r = __builtin_amdgcn_rcpf(e + 1.0f);
    return v - v * r;
}

// ---------------- LayerNorm: f32 in -> bf16 out ----------------
__global__ __launch_bounds__(256) void ln_bf16_k(const float* __restrict__ x,
                                                 const float* __restrict__ g,
                                                 const float* __restrict__ b,
                                                 u16* __restrict__ y) {
    int row = blockIdx.x;
    int tid = threadIdx.x;
    const float* xr = x + (size_t)row * D_;
    f32x4 v = *(const f32x4*)(xr + tid * 4);
    float s = v.x + v.y + v.z + v.w;
    float ss = v.x * v.x + v.y * v.y + v.z * v.z + v.w * v.w;
    for (int off = 32; off > 0; off >>= 1) {
        s += __shfl_down(s, off, 64);
        ss += __shfl_down(ss, off, 64);
    }
    __shared__ float rs[4], rss[4];
    int lane = tid & 63, wid = tid >> 6;
    if (lane == 0) { rs[wid] = s; rss[wid] = ss; }
    __syncthreads();
    s = rs[0] + rs[1] + rs[2] + rs[3];
    ss = rss[0] + rss[1] + rss[2] + rss[3];
    float mu = s * (1.0f / D_);
    float var = ss * (1.0f / D_) - mu * mu;
    float inv = rsqrtf(var + 1e-6f);
    f32x4 gg = *(const f32x4*)(g + tid * 4);
    f32x4 bb = *(const f32x4*)(b + tid * 4);
    bf16x4 o = {(__bf16)((v.x - mu) * inv * gg.x + bb.x),
                (__bf16)((v.y - mu) * inv * gg.y + bb.y),
                (__bf16)((v.z - mu) * inv * gg.z + bb.z),
                (__bf16)((v.w - mu) * inv * gg.w + bb.w)};
    *(bf16x4*)(y + (size_t)row * D_ + tid * 4) = o;
}

// ---------------- bias pack: bqkv = [bq*C2|bk|bv] ----------------
__global__ void pack3_k(const float* __restrict__ a, const float* __restrict__ b,
                        const float* __restrict__ c, float* __restrict__ o, float s0) {
    const float* s = blockIdx.x == 0 ? a : (blockIdx.x == 1 ? b : c);
    float sc = blockIdx.x == 0 ? s0 : 1.0f;
    o[blockIdx.x * 1024 + threadIdx.x] = s[threadIdx.x] * sc;
}

// ---------------- weight transpose+convert: W[K,N] f32 -> Wt[N,K] bf16 (×scale) ----------------
__global__ __launch_bounds__(256) void wtrans_k(const float* __restrict__ W,
                                                u16* __restrict__ Wt, int K, int N,
                                                float scale) {
    __shared__ float T[32][33];
    int tid = threadIdx.x;
    int k0 = blockIdx.y * 32, n0 = blockIdx.x * 32;
    int r = tid >> 3, c4 = (tid & 7) * 4;
    f32x4 v = *(const f32x4*)&W[(size_t)(k0 + r) * N + n0 + c4];
    T[r][c4 + 0] = v.x; T[r][c4 + 1] = v.y; T[r][c4 + 2] = v.z; T[r][c4 + 3] = v.w;
    __syncthreads();
    int n = tid >> 3, kk = (tid & 7) * 4;
    bf16x4 o = {(__bf16)(T[kk + 0][n] * scale), (__bf16)(T[kk + 1][n] * scale),
                (__bf16)(T[kk + 2][n] * scale), (__bf16)(T[kk + 3][n] * scale)};
    *(bf16x4*)&Wt[(size_t)(n0 + n) * K + k0 + kk] = o;
}

// ---------------- merged 4x 1024x1024 transpose: Wq,Wk,Wv,Wo -> Wqkvt[4*D*D] ----------------
__global__ __launch_bounds__(256) void wtrans4_k(const float* __restrict__ W0,
                                                 const float* __restrict__ W1,
                                                 const float* __restrict__ W2,
                                                 const float* __restrict__ W3,
                                                 u16* __restrict__ Wt, float s0) {
    __shared__ float T[32][33];
    const float* W = blockIdx.z == 0 ? W0 : (blockIdx.z == 1 ? W1 : (blockIdx.z == 2 ? W2 : W3));
    float scale = blockIdx.z == 0 ? s0 : 1.0f;
    u16* dst = Wt + (size_t)blockIdx.z * D_ * D_;
    int tid = threadIdx.x;
    int k0 = blockIdx.y * 32, n0 = blockIdx.x * 32;
    int r = tid >> 3, c4 = (tid & 7) * 4;
    f32x4 v = *(const f32x4*)&W[(size_t)(k0 + r) * D_ + n0 + c4];
    T[r][c4 + 0] = v.x; T[r][c4 + 1] = v.y; T[r][c4 + 2] = v.z; T[r][c4 + 3] = v.w;
    __syncthreads();
    int n = tid >> 3, kk = (tid & 7) * 4;
    bf16x4 o = {(__bf16)(T[kk + 0][n] * scale), (__bf16)(T[kk + 1][n] * scale),
                (__bf16)(T[kk + 2][n] * scale), (__bf16)(T[kk + 3][n] * scale)};
    *(bf16x4*)&dst[(size_t)(n0 + n) * D_ + k0 + kk] = o;
}

// ---------------- bf16 MFMA GEMM, depth-2 prefetch + chunk-XOR LDS swizzle (128x128) ----------------
// C[M,N] = A[M,K] @ Wt[N,K]^T (+epilogue)
// EPI: 0 = +bias -> bf16, with fused sigma-permuted V-transpose for c >= 2048 (QKV only);
//      1 = gelu(+bias) -> bf16 ; 2 = +bias +res -> f32
template <int EPI>
__global__ __launch_bounds__(256) void gemm_bf16(const u16* __restrict__ A,
                                                 const u16* __restrict__ Wt,
                                                 const float* __restrict__ bias,
                                                 const float* __restrict__ res,
                                                 void* __restrict__ Cout,
                                                 u16* __restrict__ vt,
                                                 int M, int N, int K) {
    __shared__ u16 As[3][128 * 32];   // 3-deep rotation, 8KB each (48KB total -> 3 blocks/CU)
    __shared__ u16 Bs[3][128 * 32];
    const int tid = threadIdx.x;
    const int lane = tid & 63;
    const int w = tid >> 6;
    // XCD-chunked bijective remap (nwg % 8 == 0 for all our grids)
    const int nwg = gridDim.x * gridDim.y;
    int hw = blockIdx.x + gridDim.x * blockIdx.y;
    int lg = (hw & 7) * (nwg >> 3) + (hw >> 3);
    const int row0 = (lg / gridDim.x) * 128;
    const int col0 = (lg % gridDim.x) * 128;
    const int l15 = lane & 15, l16 = lane >> 4;
    const int wr = w >> 1, wc = w & 1;

    f32x4 acc[4][4];
#pragma unroll
    for (int i = 0; i < 4; ++i)
#pragma unroll
        for (int j = 0; j < 4; ++j) acc[i][j] = (f32x4){0.f, 0.f, 0.f, 0.f};

    const int srow = w * 32 + (lane >> 2);
    // chunk-XOR swizzle: source chunk = (lane&3) ^ ((lane>>3)&3)
    const size_t sboff = (size_t)(((lane & 3) ^ ((lane >> 3) & 3)) * 16);
    const char* Ag = (const char*)A + ((size_t)(row0 + srow) * K) * 2 + sboff;
    const char* Bg = (const char*)Wt + ((size_t)(col0 + srow) * K) * 2 + sboff;
    const size_t rstep = (size_t)16 * K * 2;
    const int woff = w * 2048;
    const int T = K >> 5;

#define STAGE(t, bi) do {                                      \
        size_t kb = (size_t)(t) << 6;                          \
        char* asw = (char*)As + (bi) * 8192 + woff;            \
        char* bsw = (char*)Bs + (bi) * 8192 + woff;            \
        gload16(Ag + kb, asw);                                 \
        gload16(Ag + kb + rstep, asw + 1024);                  \
        gload16(Bg + kb, bsw);                                 \
        gload16(Bg + kb + rstep, bsw + 1024);                  \
    } while (0)

    STAGE(0, 0);
    STAGE(1, 1);
    asm volatile("s_waitcnt vmcnt(4)" ::: "memory");   // tile 0 landed; tile 1 in flight
    __builtin_amdgcn_s_barrier();
    __builtin_amdgcn_sched_barrier(0);

    // read-side swizzled chunk offset
    const int ksw = (l16 ^ ((l15 >> 1) & 3)) << 4;
    int bi = 0;
    for (int t = 0; t < T; ++t) {
        if (t + 2 < T) {
            int nb = bi + 2; if (nb >= 3) nb -= 3;
            STAGE(t + 2, nb);                           // prefetch stays in flight
        }
        const char* Ab = (const char*)As + bi * 8192;
        const char* Bb = (const char*)Bs + bi * 8192;
        bf16x8 af[4], bfr[4];
#pragma unroll
        for (int f = 0; f < 4; ++f) {
            af[f] = *(const bf16x8*)(Ab + (size_t)(wr * 64 + f * 16 + l15) * 64 + ksw);
            bfr[f] = *(const bf16x8*)(Bb + (size_t)(wc * 64 + f * 16 + l15) * 64 + ksw);
        }
        __builtin_amdgcn_s_setprio(1);
#pragma unroll
        for (int fi = 0; fi < 4; ++fi)
#pragma unroll
            for (int fj = 0; fj < 4; ++fj)
                acc[fi][fj] = __builtin_amdgcn_mfma_f32_16x16x32_bf16(af[fi], bfr[fj], acc[fi][fj], 0, 0, 0);
        __builtin_amdgcn_s_setprio(0);
        if (t + 2 < T) {
            asm volatile("s_waitcnt vmcnt(4)" ::: "memory");   // tile t+1 landed, t+2 in flight
        } else {
            asm volatile("s_waitcnt vmcnt(0)" ::: "memory");   // tail drain
        }
        __builtin_amdgcn_s_barrier();
        __builtin_amdgcn_sched_barrier(0);
        if (++bi >= 3) bi = 0;
    }
#undef STAGE

    const int rb = row0 + wr * 64 + (l16 << 2);
    const int cb = col0 + wc * 64 + l15;
#pragma unroll
    for (int fi = 0; fi < 4; ++fi)
#pragma unroll
        for (int fj = 0; fj < 4; ++fj) {
            int c = cb + fj * 16;
            float bv = bias[c];
            if (EPI == 0 && c >= 2048) {
                // fused V transpose: Vt[(b*16+h)*64+dh][sigma(s)..+3] (sigma keeps bits 0-1)
                int hh = (c - 2048) >> 6, dh = (c - 2048) & 63;
                int rbase = rb + fi * 16;
                int bb = rbase >> 11, s = rbase & 2047;
                int sp = (s & ~63) | (s & 51) | (((s >> 2) & 1) << 3) | (((s >> 3) & 1) << 2);
                bf16x4 pk = {(__bf16)(acc[fi][fj][0] + bv), (__bf16)(acc[fi][fj][1] + bv),
                             (__bf16)(acc[fi][fj][2] + bv), (__bf16)(acc[fi][fj][3] + bv)};
                *(bf16x4*)(vt + (((size_t)((bb * 16 + hh) * 64 + dh)) << 11) + sp) = pk;
                continue;
            }
#pragma unroll
            for (int rr = 0; rr < 4; ++rr) {
                int r = rb + fi * 16 + rr;
                float v = acc[fi][fj][rr] + bv;
                if (EPI == 1) v = gelu_f(v);
                if (EPI == 2) {
                    v += res[(size_t)r * N + c];
                    ((float*)Cout)[(size_t)r * N + c] = v;
                } else {
                    ((__bf16*)Cout)[(size_t)r * N + c] = (__bf16)v;
                }
            }
        }
}

// ---------------- MFMA flash attention: 32 q/wave, 32x32x16, in-register P ----------------
// Q pre-scaled by 0.125*log2(e) at projection -> P = exp2(score) directly.
// No max-tracking; row-sum via ones-MFMA.
__global__ __launch_bounds__(256) void attn_mfma(const u16* __restrict__ QKV,
                                                 const u16* __restrict__ Vt,
                                                 u16* __restrict__ O) {
    __shared__ u16 Ks[2][64 * 64];
    __shared__ u16 Vs[2][64 * 64];
    const int tid = threadIdx.x, lane = tid & 63, w = tid >> 6;
    int hw = blockIdx.x + gridDim.x * blockIdx.y;
    int lg = (hw & 7) * 128 + (hw >> 3);
    const int bh = lg >> 4, b = bh >> 4, h = bh & 15;
    const int q0 = (lg & 15) * 128;
    const int l31 = lane & 31, lh = lane >> 5;

    const u16* Qp = QKV + (size_t)(b * S_ + q0 + w * 32 + l31) * 3072 + h * 64 + lh * 8;
    bf16x8 qf[4];
    qf[0] = *(const bf16x8*)(Qp);
    qf[1] = *(const bf16x8*)(Qp + 16);
    qf[2] = *(const bf16x8*)(Qp + 32);
    qf[3] = *(const bf16x8*)(Qp + 48);

    f32x16 oacc[2];
    f32x16 lacc;
#pragma unroll
    for (int i = 0; i < 16; ++i) { oacc[0][i] = 0.f; oacc[1][i] = 0.f; lacc[i] = 0.f; }
    bf16x8 ones;
#pragma unroll
    for (int j = 0; j < 8; ++j) ones[j] = (__bf16)1.0f;

    const int sr = lane >> 3;
    const size_t soff = (size_t)(((lane & 7) ^ sr) << 4);
    const char* Kg = (const char*)QKV + ((size_t)b * S_ * 3072 + 1024 + h * 64) * 2;
    const char* Vg = (const char*)Vt + (size_t)bh * 64 * S_ * 2;

    const char* kp0 = Kg + (size_t)(w * 16 + sr) * 6144 + soff;
    const char* kp1 = kp0 + 8 * 6144;
    const char* vp0 = Vg + (size_t)(w * 16 + sr) * 4096 + soff;
    const char* vp1 = vp0 + 8 * 4096;
    const size_t KADV = 64 * 6144;
    const size_t VADV = 128;
    char* ksA = (char*)Ks[0] + w * 2048;
    char* ksB = (char*)Ks[1] + w * 2048;
    char* vsA = (char*)Vs[0] + w * 2048;
    char* vsB = (char*)Vs[1] + w * 2048;

    gload16(kp0, ksA); gload16(kp1, ksA + 1024);
    gload16(vp0, vsA); gload16(vp1, vsA + 1024);
    kp0 += KADV; kp1 += KADV; vp0 += VADV; vp1 += VADV;
    __syncthreads();

    for (int kt = 0; kt < S_ / 64; ++kt) {
        const int cur = kt & 1;
        if (kt < S_ / 64 - 1) {
            char* kd = cur ? ksA : ksB;
            char* vd = cur ? vsA : vsB;
            gload16(kp0, kd); gload16(kp1, kd + 1024);
            gload16(vp0, vd); gload16(vp1, vd + 1024);
            kp0 += KADV; kp1 += KADV; vp0 += VADV; vp1 += VADV;
        }

        const char* Kb_ = (const char*)Ks[cur];
        f32x16 sfr[2];
        __builtin_amdgcn_s_setprio(1);
#pragma unroll
        for (int kh = 0; kh < 2; ++kh) {
            int r = kh * 32 + l31;
            int rsw = (r & 7) << 4;
            const char* Kr = Kb_ + r * 128;
            f32x16 t;
#pragma unroll
            for (int i = 0; i < 16; ++i) t[i] = 0.f;
#pragma unroll
            for (int ds = 0; ds < 4; ++ds) {
                bf16x8 kf = *(const bf16x8*)(Kr + ((((ds * 2 + lh) << 4)) ^ rsw));
                t = __builtin_amdgcn_mfma_f32_32x32x16_bf16(kf, qf[ds], t, 0, 0, 0);
            }
            sfr[kh] = t;
        }
        __builtin_amdgcn_s_setprio(0);

        float pv0[16], pv1[16];
#pragma unroll
        for (int i = 0; i < 16; ++i) {
            pv0[i] = __builtin_amdgcn_exp2f(sfr[0][i]);
            pv1[i] = __builtin_amdgcn_exp2f(sfr[1][i]);
        }

        bf16x8 pf[4];
#pragma unroll
        for (int j = 0; j < 8; ++j) {
            pf[0][j] = (__bf16)pv0[j];
            pf[1][j] = (__bf16)pv0[8 + j];
            pf[2][j] = (__bf16)pv1[j];
            pf[3][j] = (__bf16)pv1[8 + j];
        }

        {
            const char* Vb_ = (const char*)Vs[cur];
            __builtin_amdgcn_s_setprio(1);
#pragma unroll
            for (int ks = 0; ks < 4; ++ks)
                lacc = __builtin_amdgcn_mfma_f32_32x32x16_bf16(ones, pf[ks], lacc, 0, 0, 0);
#pragma unroll
            for (int dh = 0; dh < 2; ++dh) {
                int r = dh * 32 + l31;
                int rsw = (r & 7) << 4;
                const char* Vr = Vb_ + r * 128;
#pragma unroll
                for (int ks = 0; ks < 4; ++ks) {
                    bf16x8 vf = *(const bf16x8*)(Vr + ((((ks * 2 + lh) << 4)) ^ rsw));
                    oacc[dh] = __builtin_amdgcn_mfma_f32_32x32x16_bf16(vf, pf[ks], oacc[dh], 0, 0, 0);
                }
            }
            __builtin_amdgcn_s_setprio(0);
        }
        __syncthreads();
    }

    float invl = 1.0f / lacc[0];
    char* Og = (char*)O + ((size_t)(b * S_ + q0 + w * 32 + l31) * 1024 + h * 64) * 2;
#pragma unroll
    for (int dh = 0; dh < 2; ++dh)
#pragma unroll
        for (int t4 = 0; t4 < 4; ++t4) {
            int db = dh * 32 + t4 * 8 + lh * 4;
            bf16x4 ov = {(__bf16)(oacc[dh][t4 * 4] * invl),
                         (__bf16)(oacc[dh][t4 * 4 + 1] * invl),
                         (__bf16)(oacc[dh][t4 * 4 + 2] * invl),
                         (__bf16)(oacc[dh][t4 * 4 + 3] * invl)};
            *(bf16x4*)(Og + db * 2) = ov;
        }
}

// ---------------- launch ----------------
extern "C" void kernel_launch(void* const* d_in, const int* in_sizes, int n_in,
                              void* d_out, int out_size, void* d_ws, size_t ws_size,
                              hipStream_t stream) {
    const float* x     = (const float*)d_in[0];
    const float* Wq    = (const float*)d_in[1];
    const float* bq    = (const float*)d_in[2];
    const float* Wk    = (const float*)d_in[3];
    const float* bk    = (const float*)d_in[4];
    const float* Wv    = (const float*)d_in[5];
    const float* bv    = (const float*)d_in[6];
    const float* Wo    = (const float*)d_in[7];
    const float* bo    = (const float*)d_in[8];
    const float* ln1_g = (const float*)d_in[9];
    const float* ln1_b = (const float*)d_in[10];
    const float* ln2_g = (const float*)d_in[11];
    const float* ln2_b = (const float*)d_in[12];
    const float* W1    = (const float*)d_in[13];
    const float* b1    = (const float*)d_in[14];
    const float* W2    = (const float*)d_in[15];
    const float* b2    = (const float*)d_in[16];
    float* out = (float*)d_out;
    const float C2 = 0.18033688011112f;   // 0.125 * log2(e)

    const size_t MB = 1ull << 20;
    char* ws = (char*)d_ws;
    u16* QKVb = (u16*)(ws + 0 * MB);      // 48MB [8192][3072] (V region unused)
    u16* aout = (u16*)(ws + 48 * MB);     // 16MB [8192][1024]
    u16* mid  = (u16*)(ws + 0 * MB);      // 64MB [8192][4096]
    u16* Vt   = (u16*)(ws + 64 * MB);     // 16MB (inside x2 region; dead once x2 written)
    float* x2 = (float*)(ws + 64 * MB);   // 32MB f32 (written at out-proj, after attn)
    float* bqkv = (float*)(ws + 80 * MB); // 12KB (inside x2 region; read only during QKV)
    u16* xn   = (u16*)(ws + 96 * MB);     // 16MB
    u16* xn2  = (u16*)(ws + 96 * MB);     // reuses xn after QKV
    u16* Wqkvt = (u16*)(ws + 112 * MB);   // 8MB [4096][1024]: Wq,Wk,Wv,Wo transposed
    u16* Wot  = Wqkvt + (size_t)3 * D_ * D_;
    u16* W1t  = (u16*)(ws + 112 * MB);    // 8MB (reuses Wqkvt+Wot after out-proj)
    u16* W2t  = (u16*)(ws + 120 * MB);    // 8MB

    // weight conversions + bias pack (Wq/bq pre-scaled by C2); 4x 1024x1024 merged
    wtrans4_k<<<dim3(32, 32, 4), 256, 0, stream>>>(Wq, Wk, Wv, Wo, Wqkvt, C2);
    wtrans_k<<<dim3(32, 128), 256, 0, stream>>>(W2, W2t, MLP_, D_, 1.0f);
    pack3_k<<<3, 1024, 0, stream>>>(bq, bk, bv, bqkv, C2);

    // LN1
    ln_bf16_k<<<MROWS, 256, 0, stream>>>(x, ln1_g, ln1_b, xn);
    // fused QKV projection with fused sigma-permuted V transpose
    gemm_bf16<0><<<dim3(24, 64), 256, 0, stream>>>(xn, Wqkvt, bqkv, nullptr, QKVb, Vt, MROWS, 3072, D_);
    // attention (128 queries/block)
    attn_mfma<<<dim3(16, 64), 256, 0, stream>>>(QKVb, Vt, aout);
    // out projection + residual -> x2 (f32) [overwrites Vt+bqkv, both dead]
    gemm_bf16<2><<<dim3(8, 64), 256, 0, stream>>>(aout, Wot, bo, x, x2, nullptr, MROWS, D_, D_);
    // W1 transpose, LN2
    wtrans_k<<<dim3(128, 32), 256, 0, stream>>>(W1, W1t, D_, MLP_, 1.0f);
    ln_bf16_k<<<MROWS, 256, 0, stream>>>(x2, ln2_g, ln2_b, xn2);
    // MLP
    gemm_bf16<1><<<dim3(32, 64), 256, 0, stream>>>(xn2, W1t, b1, nullptr, mid, nullptr, MROWS, MLP_, D_);
    gemm_bf16<2><<<dim3(8, 64), 256, 0, stream>>>(mid, W2t, b2, x2, (void*)out, nullptr, MROWS, D_, MLP_);
}

// Round 18
// 405.588 us; speedup vs baseline: 1.1119x; 1.0188x over previous
//
#include <hip/hip_runtime.h>
#include <math.h>

#define B_ 4
#define S_ 2048
#define D_ 1024
#define H_ 16
#define MLP_ 4096
#define MROWS 8192

typedef __attribute__((ext_vector_type(4))) float f32x4;
typedef __attribute__((ext_vector_type(16))) float f32x16;
typedef __attribute__((ext_vector_type(8))) __bf16 bf16x8;
typedef __attribute__((ext_vector_type(4))) __bf16 bf16x4;
typedef __attribute__((ext_vector_type(8))) unsigned short us8;
typedef unsigned short u16;
typedef unsigned int u32;

__device__ __forceinline__ void gload16(const void* g, void* l) {
    __builtin_amdgcn_global_load_lds((const __attribute__((address_space(1))) u32*)g,
                                     (__attribute__((address_space(3))) u32*)l, 16, 0, 0);
}

// fast GELU: x - x/(e+1), e = exp2(2*log2e*0.7978845608*(x + 0.044715 x^3))
__device__ __forceinline__ float gelu_f(float v) {
    float p = fmaf(v * v, 0.044715f, 1.0f);
    float e = __builtin_amdgcn_exp2f(v * 2.3022089f * p);
    float r = __builtin_amdgcn_rcpf(e + 1.0f);
    return v - v * r;
}

// ---------------- LayerNorm: f32/bf16 in -> bf16 out ----------------
template <int BFIN>
__global__ __launch_bounds__(256) void ln_bf16_k(const void* __restrict__ xv,
                                                 const float* __restrict__ g,
                                                 const float* __restrict__ b,
                                                 u16* __restrict__ y) {
    int row = blockIdx.x;
    int tid = threadIdx.x;
    f32x4 v;
    if (BFIN) {
        bf16x4 bv = *(const bf16x4*)((const u16*)xv + (size_t)row * D_ + tid * 4);
        v.x = (float)bv.x; v.y = (float)bv.y; v.z = (float)bv.z; v.w = (float)bv.w;
    } else {
        v = *(const f32x4*)((const float*)xv + (size_t)row * D_ + tid * 4);
    }
    float s = v.x + v.y + v.z + v.w;
    float ss = v.x * v.x + v.y * v.y + v.z * v.z + v.w * v.w;
    for (int off = 32; off > 0; off >>= 1) {
        s += __shfl_down(s, off, 64);
        ss += __shfl_down(ss, off, 64);
    }
    __shared__ float rs[4], rss[4];
    int lane = tid & 63, wid = tid >> 6;
    if (lane == 0) { rs[wid] = s; rss[wid] = ss; }
    __syncthreads();
    s = rs[0] + rs[1] + rs[2] + rs[3];
    ss = rss[0] + rss[1] + rss[2] + rss[3];
    float mu = s * (1.0f / D_);
    float var = ss * (1.0f / D_) - mu * mu;
    float inv = rsqrtf(var + 1e-6f);
    f32x4 gg = *(const f32x4*)(g + tid * 4);
    f32x4 bb = *(const f32x4*)(b + tid * 4);
    bf16x4 o = {(__bf16)((v.x - mu) * inv * gg.x + bb.x),
                (__bf16)((v.y - mu) * inv * gg.y + bb.y),
                (__bf16)((v.z - mu) * inv * gg.z + bb.z),
                (__bf16)((v.w - mu) * inv * gg.w + bb.w)};
    *(bf16x4*)(y + (size_t)row * D_ + tid * 4) = o;
}

// ---------------- bias pack: bqkv = [bq*C2|bk|bv] ----------------
__global__ void pack3_k(const float* __restrict__ a, const float* __restrict__ b,
                        const float* __restrict__ c, float* __restrict__ o, float s0) {
    const float* s = blockIdx.x == 0 ? a : (blockIdx.x == 1 ? b : c);
    float sc = blockIdx.x == 0 ? s0 : 1.0f;
    o[blockIdx.x * 1024 + threadIdx.x] = s[threadIdx.x] * sc;
}

// ---------------- weight transpose+convert: W[K,N] f32 -> Wt[N,K] bf16 (×scale) ----------------
__global__ __launch_bounds__(256) void wtrans_k(const float* __restrict__ W,
                                                u16* __restrict__ Wt, int K, int N,
                                                float scale) {
    __shared__ float T[32][33];
    int tid = threadIdx.x;
    int k0 = blockIdx.y * 32, n0 = blockIdx.x * 32;
    int r = tid >> 3, c4 = (tid & 7) * 4;
    f32x4 v = *(const f32x4*)&W[(size_t)(k0 + r) * N + n0 + c4];
    T[r][c4 + 0] = v.x; T[r][c4 + 1] = v.y; T[r][c4 + 2] = v.z; T[r][c4 + 3] = v.w;
    __syncthreads();
    int n = tid >> 3, kk = (tid & 7) * 4;
    bf16x4 o = {(__bf16)(T[kk + 0][n] * scale), (__bf16)(T[kk + 1][n] * scale),
                (__bf16)(T[kk + 2][n] * scale), (__bf16)(T[kk + 3][n] * scale)};
    *(bf16x4*)&Wt[(size_t)(n0 + n) * K + k0 + kk] = o;
}

// ---------------- merged 4x 1024x1024 transpose: Wq,Wk,Wv,Wo -> Wqkvt[4*D*D] ----------------
__global__ __launch_bounds__(256) void wtrans4_k(const float* __restrict__ W0,
                                                 const float* __restrict__ W1,
                                                 const float* __restrict__ W2,
                                                 const float* __restrict__ W3,
                                                 u16* __restrict__ Wt, float s0) {
    __shared__ float T[32][33];
    const float* W = blockIdx.z == 0 ? W0 : (blockIdx.z == 1 ? W1 : (blockIdx.z == 2 ? W2 : W3));
    float scale = blockIdx.z == 0 ? s0 : 1.0f;
    u16* dst = Wt + (size_t)blockIdx.z * D_ * D_;
    int tid = threadIdx.x;
    int k0 = blockIdx.y * 32, n0 = blockIdx.x * 32;
    int r = tid >> 3, c4 = (tid & 7) * 4;
    f32x4 v = *(const f32x4*)&W[(size_t)(k0 + r) * D_ + n0 + c4];
    T[r][c4 + 0] = v.x; T[r][c4 + 1] = v.y; T[r][c4 + 2] = v.z; T[r][c4 + 3] = v.w;
    __syncthreads();
    int n = tid >> 3, kk = (tid & 7) * 4;
    bf16x4 o = {(__bf16)(T[kk + 0][n] * scale), (__bf16)(T[kk + 1][n] * scale),
                (__bf16)(T[kk + 2][n] * scale), (__bf16)(T[kk + 3][n] * scale)};
    *(bf16x4*)&dst[(size_t)(n0 + n) * D_ + k0 + kk] = o;
}

// ---------------- bf16 MFMA GEMM, depth-2 prefetch + chunk-XOR LDS swizzle (128x128) ----------------
// C[M,N] = A[M,K] @ Wt[N,K]^T (+epilogue)
// EPI: 0 = +bias -> bf16, fused sigma-V-transpose for c >= 2048 (QKV only)
//      1 = gelu(+bias) -> bf16
//      3 = +bias +res(f32) -> bf16   (out-proj: bf16 residual stream)
//      4 = +bias +res(bf16) -> f32   (MLP2: final output)
template <int EPI>
__global__ __launch_bounds__(256) void gemm_bf16(const u16* __restrict__ A,
                                                 const u16* __restrict__ Wt,
                                                 const float* __restrict__ bias,
                                                 const void* __restrict__ res,
                                                 void* __restrict__ Cout,
                                                 u16* __restrict__ vt,
                                                 int M, int N, int K) {
    __shared__ u16 As[3][128 * 32];   // 3-deep rotation, 8KB each (48KB total -> 3 blocks/CU)
    __shared__ u16 Bs[3][128 * 32];
    const int tid = threadIdx.x;
    const int lane = tid & 63;
    const int w = tid >> 6;
    // XCD-chunked bijective remap (nwg % 8 == 0 for all our grids)
    const int nwg = gridDim.x * gridDim.y;
    int hw = blockIdx.x + gridDim.x * blockIdx.y;
    int lg = (hw & 7) * (nwg >> 3) + (hw >> 3);
    const int row0 = (lg / gridDim.x) * 128;
    const int col0 = (lg % gridDim.x) * 128;
    const int l15 = lane & 15, l16 = lane >> 4;
    const int wr = w >> 1, wc = w & 1;

    f32x4 acc[4][4];
#pragma unroll
    for (int i = 0; i < 4; ++i)
#pragma unroll
        for (int j = 0; j < 4; ++j) acc[i][j] = (f32x4){0.f, 0.f, 0.f, 0.f};

    const int srow = w * 32 + (lane >> 2);
    // chunk-XOR swizzle: source chunk = (lane&3) ^ ((lane>>3)&3)
    const size_t sboff = (size_t)(((lane & 3) ^ ((lane >> 3) & 3)) * 16);
    const char* Ag = (const char*)A + ((size_t)(row0 + srow) * K) * 2 + sboff;
    const char* Bg = (const char*)Wt + ((size_t)(col0 + srow) * K) * 2 + sboff;
    const size_t rstep = (size_t)16 * K * 2;
    const int woff = w * 2048;
    const int T = K >> 5;

#define STAGE(t, bi) do {                                      \
        size_t kb = (size_t)(t) << 6;                          \
        char* asw = (char*)As + (bi) * 8192 + woff;            \
        char* bsw = (char*)Bs + (bi) * 8192 + woff;            \
        gload16(Ag + kb, asw);                                 \
        gload16(Ag + kb + rstep, asw + 1024);                  \
        gload16(Bg + kb, bsw);                                 \
        gload16(Bg + kb + rstep, bsw + 1024);                  \
    } while (0)

    STAGE(0, 0);
    STAGE(1, 1);
    asm volatile("s_waitcnt vmcnt(4)" ::: "memory");   // tile 0 landed; tile 1 in flight
    __builtin_amdgcn_s_barrier();
    __builtin_amdgcn_sched_barrier(0);

    // read-side swizzled chunk offset
    const int ksw = (l16 ^ ((l15 >> 1) & 3)) << 4;
    int bi = 0;
    for (int t = 0; t < T; ++t) {
        if (t + 2 < T) {
            int nb = bi + 2; if (nb >= 3) nb -= 3;
            STAGE(t + 2, nb);                           // prefetch stays in flight
        }
        const char* Ab = (const char*)As + bi * 8192;
        const char* Bb = (const char*)Bs + bi * 8192;
        bf16x8 af[4], bfr[4];
#pragma unroll
        for (int f = 0; f < 4; ++f) {
            af[f] = *(const bf16x8*)(Ab + (size_t)(wr * 64 + f * 16 + l15) * 64 + ksw);
            bfr[f] = *(const bf16x8*)(Bb + (size_t)(wc * 64 + f * 16 + l15) * 64 + ksw);
        }
        __builtin_amdgcn_s_setprio(1);
#pragma unroll
        for (int fi = 0; fi < 4; ++fi)
#pragma unroll
            for (int fj = 0; fj < 4; ++fj)
                acc[fi][fj] = __builtin_amdgcn_mfma_f32_16x16x32_bf16(af[fi], bfr[fj], acc[fi][fj], 0, 0, 0);
        __builtin_amdgcn_s_setprio(0);
        if (t + 2 < T) {
            asm volatile("s_waitcnt vmcnt(4)" ::: "memory");   // tile t+1 landed, t+2 in flight
        } else {
            asm volatile("s_waitcnt vmcnt(0)" ::: "memory");   // tail drain
        }
        __builtin_amdgcn_s_barrier();
        __builtin_amdgcn_sched_barrier(0);
        if (++bi >= 3) bi = 0;
    }
#undef STAGE

    const int rb = row0 + wr * 64 + (l16 << 2);
    const int cb = col0 + wc * 64 + l15;
#pragma unroll
    for (int fi = 0; fi < 4; ++fi)
#pragma unroll
        for (int fj = 0; fj < 4; ++fj) {
            int c = cb + fj * 16;
            float bv = bias[c];
            if (EPI == 0 && c >= 2048) {
                // fused V transpose: Vt[(b*16+h)*64+dh][sigma(s)..+3] (sigma keeps bits 0-1)
                int hh = (c - 2048) >> 6, dh = (c - 2048) & 63;
                int rbase = rb + fi * 16;
                int bb = rbase >> 11, s = rbase & 2047;
                int sp = (s & ~63) | (s & 51) | (((s >> 2) & 1) << 3) | (((s >> 3) & 1) << 2);
                bf16x4 pk = {(__bf16)(acc[fi][fj][0] + bv), (__bf16)(acc[fi][fj][1] + bv),
                             (__bf16)(acc[fi][fj][2] + bv), (__bf16)(acc[fi][fj][3] + bv)};
                *(bf16x4*)(vt + (((size_t)((bb * 16 + hh) * 64 + dh)) << 11) + sp) = pk;
                continue;
            }
#pragma unroll
            for (int rr = 0; rr < 4; ++rr) {
                int r = rb + fi * 16 + rr;
                float v = acc[fi][fj][rr] + bv;
                if (EPI == 1) v = gelu_f(v);
                if (EPI == 3) {
                    v += ((const float*)res)[(size_t)r * N + c];
                    ((__bf16*)Cout)[(size_t)r * N + c] = (__bf16)v;
                } else if (EPI == 4) {
                    v += (float)((const __bf16*)res)[(size_t)r * N + c];
                    ((float*)Cout)[(size_t)r * N + c] = v;
                } else {
                    ((__bf16*)Cout)[(size_t)r * N + c] = (__bf16)v;
                }
            }
        }
}

// ---------------- MFMA flash attention: 32 q/wave, 32x32x16, in-register P ----------------
// Q pre-scaled by 0.125*log2(e) at projection -> P = exp2(score) directly.
// No max-tracking; row-sum via ones-MFMA.
__global__ __launch_bounds__(256) void attn_mfma(const u16* __restrict__ QKV,
                                                 const u16* __restrict__ Vt,
                                                 u16* __restrict__ O) {
    __shared__ u16 Ks[2][64 * 64];
    __shared__ u16 Vs[2][64 * 64];
    const int tid = threadIdx.x, lane = tid & 63, w = tid >> 6;
    int hw = blockIdx.x + gridDim.x * blockIdx.y;
    int lg = (hw & 7) * 128 + (hw >> 3);
    const int bh = lg >> 4, b = bh >> 4, h = bh & 15;
    const int q0 = (lg & 15) * 128;
    const int l31 = lane & 31, lh = lane >> 5;

    const u16* Qp = QKV + (size_t)(b * S_ + q0 + w * 32 + l31) * 3072 + h * 64 + lh * 8;
    bf16x8 qf[4];
    qf[0] = *(const bf16x8*)(Qp);
    qf[1] = *(const bf16x8*)(Qp + 16);
    qf[2] = *(const bf16x8*)(Qp + 32);
    qf[3] = *(const bf16x8*)(Qp + 48);

    f32x16 oacc[2];
    f32x16 lacc;
#pragma unroll
    for (int i = 0; i < 16; ++i) { oacc[0][i] = 0.f; oacc[1][i] = 0.f; lacc[i] = 0.f; }
    bf16x8 ones;
#pragma unroll
    for (int j = 0; j < 8; ++j) ones[j] = (__bf16)1.0f;

    const int sr = lane >> 3;
    const size_t soff = (size_t)(((lane & 7) ^ sr) << 4);
    const char* Kg = (const char*)QKV + ((size_t)b * S_ * 3072 + 1024 + h * 64) * 2;
    const char* Vg = (const char*)Vt + (size_t)bh * 64 * S_ * 2;

    const char* kp0 = Kg + (size_t)(w * 16 + sr) * 6144 + soff;
    const char* kp1 = kp0 + 8 * 6144;
    const char* vp0 = Vg + (size_t)(w * 16 + sr) * 4096 + soff;
    const char* vp1 = vp0 + 8 * 4096;
    const size_t KADV = 64 * 6144;
    const size_t VADV = 128;
    char* ksA = (char*)Ks[0] + w * 2048;
    char* ksB = (char*)Ks[1] + w * 2048;
    char* vsA = (char*)Vs[0] + w * 2048;
    char* vsB = (char*)Vs[1] + w * 2048;

    gload16(kp0, ksA); gload16(kp1, ksA + 1024);
    gload16(vp0, vsA); gload16(vp1, vsA + 1024);
    kp0 += KADV; kp1 += KADV; vp0 += VADV; vp1 += VADV;
    __syncthreads();

    for (int kt = 0; kt < S_ / 64; ++kt) {
        const int cur = kt & 1;
        if (kt < S_ / 64 - 1) {
            char* kd = cur ? ksA : ksB;
            char* vd = cur ? vsA : vsB;
            gload16(kp0, kd); gload16(kp1, kd + 1024);
            gload16(vp0, vd); gload16(vp1, vd + 1024);
            kp0 += KADV; kp1 += KADV; vp0 += VADV; vp1 += VADV;
        }

        const char* Kb_ = (const char*)Ks[cur];
        f32x16 sfr[2];
        __builtin_amdgcn_s_setprio(1);
#pragma unroll
        for (int kh = 0; kh < 2; ++kh) {
            int r = kh * 32 + l31;
            int rsw = (r & 7) << 4;
            const char* Kr = Kb_ + r * 128;
            f32x16 t;
#pragma unroll
            for (int i = 0; i < 16; ++i) t[i] = 0.f;
#pragma unroll
            for (int ds = 0; ds < 4; ++ds) {
                bf16x8 kf = *(const bf16x8*)(Kr + ((((ds * 2 + lh) << 4)) ^ rsw));
                t = __builtin_amdgcn_mfma_f32_32x32x16_bf16(kf, qf[ds], t, 0, 0, 0);
            }
            sfr[kh] = t;
        }
        __builtin_amdgcn_s_setprio(0);

        float pv0[16], pv1[16];
#pragma unroll
        for (int i = 0; i < 16; ++i) {
            pv0[i] = __builtin_amdgcn_exp2f(sfr[0][i]);
            pv1[i] = __builtin_amdgcn_exp2f(sfr[1][i]);
        }

        bf16x8 pf[4];
#pragma unroll
        for (int j = 0; j < 8; ++j) {
            pf[0][j] = (__bf16)pv0[j];
            pf[1][j] = (__bf16)pv0[8 + j];
            pf[2][j] = (__bf16)pv1[j];
            pf[3][j] = (__bf16)pv1[8 + j];
        }

        {
            const char* Vb_ = (const char*)Vs[cur];
            __builtin_amdgcn_s_setprio(1);
#pragma unroll
            for (int ks = 0; ks < 4; ++ks)
                lacc = __builtin_amdgcn_mfma_f32_32x32x16_bf16(ones, pf[ks], lacc, 0, 0, 0);
#pragma unroll
            for (int dh = 0; dh < 2; ++dh) {
                int r = dh * 32 + l31;
                int rsw = (r & 7) << 4;
                const char* Vr = Vb_ + r * 128;
#pragma unroll
                for (int ks = 0; ks < 4; ++ks) {
                    bf16x8 vf = *(const bf16x8*)(Vr + ((((ks * 2 + lh) << 4)) ^ rsw));
                    oacc[dh] = __builtin_amdgcn_mfma_f32_32x32x16_bf16(vf, pf[ks], oacc[dh], 0, 0, 0);
                }
            }
            __builtin_amdgcn_s_setprio(0);
        }
        __syncthreads();
    }

    float invl = 1.0f / lacc[0];
    char* Og = (char*)O + ((size_t)(b * S_ + q0 + w * 32 + l31) * 1024 + h * 64) * 2;
#pragma unroll
    for (int dh = 0; dh < 2; ++dh)
#pragma unroll
        for (int t4 = 0; t4 < 4; ++t4) {
            int db = dh * 32 + t4 * 8 + lh * 4;
            bf16x4 ov = {(__bf16)(oacc[dh][t4 * 4] * invl),
                         (__bf16)(oacc[dh][t4 * 4 + 1] * invl),
                         (__bf16)(oacc[dh][t4 * 4 + 2] * invl),
                         (__bf16)(oacc[dh][t4 * 4 + 3] * invl)};
            *(bf16x4*)(Og + db * 2) = ov;
        }
}

// ---------------- launch ----------------
extern "C" void kernel_launch(void* const* d_in, const int* in_sizes, int n_in,
                              void* d_out, int out_size, void* d_ws, size_t ws_size,
                              hipStream_t stream) {
    const float* x     = (const float*)d_in[0];
    const float* Wq    = (const float*)d_in[1];
    const float* bq    = (const float*)d_in[2];
    const float* Wk    = (const float*)d_in[3];
    const float* bk    = (const float*)d_in[4];
    const float* Wv    = (const float*)d_in[5];
    const float* bv    = (const float*)d_in[6];
    const float* Wo    = (const float*)d_in[7];
    const float* bo    = (const float*)d_in[8];
    const float* ln1_g = (const float*)d_in[9];
    const float* ln1_b = (const float*)d_in[10];
    const float* ln2_g = (const float*)d_in[11];
    const float* ln2_b = (const float*)d_in[12];
    const float* W1    = (const float*)d_in[13];
    const float* b1    = (const float*)d_in[14];
    const float* W2    = (const float*)d_in[15];
    const float* b2    = (const float*)d_in[16];
    float* out = (float*)d_out;
    const float C2 = 0.18033688011112f;   // 0.125 * log2(e)

    const size_t MB = 1ull << 20;
    char* ws = (char*)d_ws;
    u16* QKVb = (u16*)(ws + 0 * MB);      // 48MB [8192][3072] (V region unused)
    u16* aout = (u16*)(ws + 48 * MB);     // 16MB [8192][1024]
    u16* mid  = (u16*)(ws + 0 * MB);      // 64MB [8192][4096]
    u16* Vt   = (u16*)(ws + 64 * MB);     // 16MB (dead after attn)
    u16* x2b  = (u16*)(ws + 64 * MB);     // 16MB bf16 residual stream (overwrites Vt)
    float* bqkv = (float*)(ws + 82 * MB); // 12KB
    u16* xn   = (u16*)(ws + 96 * MB);     // 16MB
    u16* xn2  = (u16*)(ws + 96 * MB);     // reuses xn after QKV
    u16* Wqkvt = (u16*)(ws + 112 * MB);   // 8MB [4096][1024]: Wq,Wk,Wv,Wo transposed
    u16* Wot  = Wqkvt + (size_t)3 * D_ * D_;
    u16* W1t  = (u16*)(ws + 112 * MB);    // 8MB (reuses Wqkvt+Wot after out-proj)
    u16* W2t  = (u16*)(ws + 120 * MB);    // 8MB

    // weight conversions + bias pack (Wq/bq pre-scaled by C2); 4x 1024x1024 merged
    wtrans4_k<<<dim3(32, 32, 4), 256, 0, stream>>>(Wq, Wk, Wv, Wo, Wqkvt, C2);
    wtrans_k<<<dim3(32, 128), 256, 0, stream>>>(W2, W2t, MLP_, D_, 1.0f);
    pack3_k<<<3, 1024, 0, stream>>>(bq, bk, bv, bqkv, C2);

    // LN1 (f32 in)
    ln_bf16_k<0><<<MROWS, 256, 0, stream>>>(x, ln1_g, ln1_b, xn);
    // fused QKV projection with fused sigma-permuted V transpose
    gemm_bf16<0><<<dim3(24, 64), 256, 0, stream>>>(xn, Wqkvt, bqkv, nullptr, QKVb, Vt, MROWS, 3072, D_);
    // attention (128 queries/block)
    attn_mfma<<<dim3(16, 64), 256, 0, stream>>>(QKVb, Vt, aout);
    // out projection + residual(x f32) -> x2b (bf16) [overwrites Vt, dead]
    gemm_bf16<3><<<dim3(8, 64), 256, 0, stream>>>(aout, Wot, bo, x, x2b, nullptr, MROWS, D_, D_);
    // W1 transpose, LN2 (bf16 in)
    wtrans_k<<<dim3(128, 32), 256, 0, stream>>>(W1, W1t, D_, MLP_, 1.0f);
    ln_bf16_k<1><<<MROWS, 256, 0, stream>>>(x2b, ln2_g, ln2_b, xn2);
    // MLP
    gemm_bf16<1><<<dim3(32, 64), 256, 0, stream>>>(xn2, W1t, b1, nullptr, mid, nullptr, MROWS, MLP_, D_);
    gemm_bf16<4><<<dim3(8, 64), 256, 0, stream>>>(mid, W2t, b2, x2b, (void*)out, nullptr, MROWS, D_, MLP_);
}